// Round 4
// baseline (49.048 us; speedup 1.0000x reference)
//
#include <hip/hip_runtime.h>
#include <math.h>

#define BATCH   32
#define SEQ     8192
#define HID     256
#define WIN     128
#define NSL     8            // slices (blocks) per batch
#define SLROWS  32           // window rows per slice

// ws layout (bytes):
//   ws_exp : float[BATCH*256]         @ 0       (32 KB) unnormalized exp(score)
//   ws_sum : float[BATCH*NSL]         @ 32768   (1 KB)  per-slice exp sums
//   cnt    : int[BATCH]               @ 33792   (128 B) arrival counters (memset 0 per call)
//   ws_ctx : float[BATCH*NSL*HID]     @ 34816   (256 KB) per-slice context partials
#define WS_EXP_OFF  0
#define WS_SUM_OFF  32768
#define WS_CNT_OFF  33792
#define WS_CTX_OFF  34816

// ---------------------------------------------------------------------------
// Single fused kernel: 256 blocks = 32 batches x 8 window-slices, 256 threads.
//   1. zero own 1/8 of the batch's attn row
//   2. redundant p_t: full tanh(W_p h).v_p in f64 per block (W_p is L2-hot)
//   3. scores -> exp (no max-sub; scores ~N(0,1)) for 32 rows
//   4. partial context (32 rows x 256 h, coalesced)
//   5. fence + counter; last block of the batch normalizes and writes outputs
// ---------------------------------------------------------------------------
__global__ __launch_bounds__(256) void fused_local_attn(
    const float* __restrict__ h_t,    // [B, HID]
    const float* __restrict__ enc,    // [B, SEQ, HID]
    const float* __restrict__ W_p,    // [HID, HID]
    const float* __restrict__ v_p,    // [HID]
    const float* __restrict__ w_att,  // [HID]
    float* __restrict__ ctx_out,      // [B, HID]
    float* __restrict__ attn_out,     // [B, SEQ]
    float* __restrict__ ws_exp,
    float* __restrict__ ws_sum,
    float* __restrict__ ws_ctx,
    int*   __restrict__ counters)
{
    const int blk = blockIdx.x;
    const int b   = blk >> 3;
    const int s   = blk & 7;
    const int tid = threadIdx.x;

    __shared__ float  hs[HID];
    __shared__ float  wa[HID];
    __shared__ double wred[4];
    __shared__ float  partial[256];
    __shared__ float  es[SLROWS];
    __shared__ int    win_s[2];
    __shared__ int    is_last;
    __shared__ float  inv_s;

    hs[tid] = h_t[b * HID + tid];
    wa[tid] = w_att[tid];

    // ---- 1. zero this block's 1024-float segment of the attn row
    {
        float4* az = (float4*)(attn_out + (size_t)b * SEQ + (size_t)s * 1024);
        az[tid] = make_float4(0.f, 0.f, 0.f, 0.f);
    }
    __syncthreads();

    // ---- 2. p_t (redundant per block): thread = output dim j, f64 accum
    {
        const float4* wrow = (const float4*)(W_p + (size_t)tid * HID);
        double a0 = 0.0, a1 = 0.0, a2 = 0.0, a3 = 0.0;
#pragma unroll 4
        for (int k = 0; k < 64; k += 4) {
            float4 w0 = wrow[k], w1 = wrow[k+1], w2 = wrow[k+2], w3 = wrow[k+3];
            const float* h4 = &hs[4 * k];
            a0 += (double)w0.x*h4[0]  + (double)w0.y*h4[1]  + (double)w0.z*h4[2]  + (double)w0.w*h4[3];
            a1 += (double)w1.x*h4[4]  + (double)w1.y*h4[5]  + (double)w1.z*h4[6]  + (double)w1.w*h4[7];
            a2 += (double)w2.x*h4[8]  + (double)w2.y*h4[9]  + (double)w2.z*h4[10] + (double)w2.w*h4[11];
            a3 += (double)w3.x*h4[12] + (double)w3.y*h4[13] + (double)w3.z*h4[14] + (double)w3.w*h4[15];
        }
        float  t   = tanhf((float)(a0 + a1 + a2 + a3));
        double val = (double)t * (double)v_p[tid];
        // in-wave f64 reduce (64 lanes), then 4-way LDS combine
        for (int off = 32; off > 0; off >>= 1) val += __shfl_down(val, off, 64);
        if ((tid & 63) == 0) wred[tid >> 6] = val;
    }
    __syncthreads();
    if (tid == 0) {
        double x  = wred[0] + wred[1] + wred[2] + wred[3];
        float  xf = (float)x;
        float  sg = 1.0f / (1.0f + expf(-xf));     // sigmoid
        float  p  = (float)SEQ * sg;
        int pr = (int)rintf(p);                    // round-half-even == jnp.round
        pr = min(max(pr, 0), SEQ - 1);
        win_s[0] = max(pr - WIN, 0);
        win_s[1] = min(pr + WIN, SEQ);
    }
    __syncthreads();

    const int start = win_s[0];
    const int end   = win_s[1];
    const int g0    = start + s * SLROWS;          // first global row of this slice

    // ---- 3. scores: 8 threads per row, 32-float segments
    {
        const int r   = tid >> 3;                  // 0..31
        const int seg = tid & 7;
        const int g   = g0 + r;
        const int gc  = (g < end) ? g : start;     // clamp to valid row
        const float4* rowp = (const float4*)(enc + ((size_t)b * SEQ + gc) * HID + seg * 32);
        const float*  w4   = &wa[seg * 32];
        float sc = 0.f;
#pragma unroll
        for (int k = 0; k < 8; ++k) {
            float4 e = rowp[k];
            sc += e.x * w4[k*4+0] + e.y * w4[k*4+1] + e.z * w4[k*4+2] + e.w * w4[k*4+3];
        }
        partial[tid] = sc;
    }
    __syncthreads();

    if (tid < SLROWS) {
        const int base = tid * 8;
        float scr = 0.f;
#pragma unroll
        for (int k = 0; k < 8; ++k) scr += partial[base + k];
        const int g = g0 + tid;
        float ev = (g < end) ? expf(scr) : 0.f;    // no max-sub: scores ~N(0,1)
        es[tid] = ev;
        ws_exp[b * 256 + s * SLROWS + tid] = ev;
    }
    __syncthreads();

    if (tid == 0) {                                // fixed-order slice sum
        float sm = 0.f;
#pragma unroll
        for (int k = 0; k < SLROWS; ++k) sm += es[k];
        ws_sum[b * NSL + s] = sm;
    }

    // ---- 4. partial context: thread = h dim, 32 rows, coalesced
    {
        float acc = 0.f;
        if (g0 + SLROWS - 1 < end) {               // all rows valid
            const float* basep = enc + ((size_t)b * SEQ + g0) * HID + tid;
#pragma unroll
            for (int i = 0; i < SLROWS; ++i)
                acc += es[i] * basep[(size_t)i * HID];
        } else {                                   // tail: clamp (es[i]==0 there)
#pragma unroll
            for (int i = 0; i < SLROWS; ++i) {
                int g  = g0 + i;
                int gc = (g < end) ? g : start;
                acc += es[i] * enc[((size_t)b * SEQ + gc) * HID + tid];
            }
        }
        ws_ctx[((size_t)b * NSL + s) * HID + tid] = acc;
    }

    // ---- 5. release, count arrivals, last block finalizes the batch
    __threadfence();                               // release our stores (device scope)
    __syncthreads();
    if (tid == 0) is_last = (atomicAdd(&counters[b], 1) == NSL - 1);
    __syncthreads();
    if (!is_last) return;
    __threadfence();                               // acquire: see other XCDs' partials

    if (tid == 0) {
        float dsum = 0.f;
#pragma unroll
        for (int k = 0; k < NSL; ++k) dsum += ws_sum[b * NSL + k];
        inv_s = 1.0f / dsum;
    }
    __syncthreads();

    const float inv = inv_s;
    float acc = 0.f;
#pragma unroll
    for (int k = 0; k < NSL; ++k)
        acc += ws_ctx[((size_t)b * NSL + k) * HID + tid];
    ctx_out[b * HID + tid] = acc * inv;

    const int L = end - start;
    if (tid < L)
        attn_out[(size_t)b * SEQ + start + tid] = ws_exp[b * 256 + tid] * inv;
}

extern "C" void kernel_launch(void* const* d_in, const int* in_sizes, int n_in,
                              void* d_out, int out_size, void* d_ws, size_t ws_size,
                              hipStream_t stream) {
    const float* h_t   = (const float*)d_in[0];   // [B, HID]
    const float* enc   = (const float*)d_in[1];   // [B, SEQ, HID]
    const float* W_p   = (const float*)d_in[2];   // [HID, HID]
    const float* v_p   = (const float*)d_in[3];   // [HID]
    const float* w_att = (const float*)d_in[4];   // [HID]

    float* ctx_out  = (float*)d_out;                  // [B, HID]
    float* attn_out = (float*)d_out + BATCH * HID;    // [B, SEQ]

    char*  ws       = (char*)d_ws;
    float* ws_exp   = (float*)(ws + WS_EXP_OFF);
    float* ws_sum   = (float*)(ws + WS_SUM_OFF);
    int*   counters = (int*)  (ws + WS_CNT_OFF);
    float* ws_ctx   = (float*)(ws + WS_CTX_OFF);

    hipMemsetAsync(counters, 0, BATCH * sizeof(int), stream);
    fused_local_attn<<<BATCH * NSL, 256, 0, stream>>>(
        h_t, enc, W_p, v_p, w_att, ctx_out, attn_out,
        ws_exp, ws_sum, ws_ctx, counters);
}

// Round 5
// 19.159 us; speedup vs baseline: 2.5600x; 2.5600x over previous
//
#include <hip/hip_runtime.h>
#include <math.h>

#define BATCH   32
#define SEQ     8192
#define HID     256
#define WIN     128
#define NSL     8            // slices (blocks) per batch
#define SLROWS  32           // window rows per slice

// ws layout (bytes):
//   ws_exp : float[BATCH*256]       @ 0       (32 KB) unnormalized exp(score)
//   ws_sum : float[BATCH*NSL]       @ 32768   (1 KB)  per-slice exp sums
//   ws_win : int2[BATCH]            @ 33792   (256 B) window bounds (written by slice 0)
//   ws_ctx : float[BATCH*NSL*HID]   @ 34816   (256 KB) per-slice context partials
#define WS_EXP_OFF  0
#define WS_SUM_OFF  32768
#define WS_WIN_OFF  33792
#define WS_CTX_OFF  34816

// ---------------------------------------------------------------------------
// K_slice: 256 blocks = 32 batches x 8 window-slices, 256 threads.
// Each block independently: zeroes its attn segment, recomputes p_t (f64,
// redundant -> no cross-block dependency), scores/exp for its 32 rows,
// fixed-order slice sum, partial context. NO fences, NO atomics — the
// following kernel launch boundary provides ordering + visibility.
// ---------------------------------------------------------------------------
__global__ __launch_bounds__(256) void k_slice(
    const float* __restrict__ h_t,    // [B, HID]
    const float* __restrict__ enc,    // [B, SEQ, HID]
    const float* __restrict__ W_p,    // [HID, HID]
    const float* __restrict__ v_p,    // [HID]
    const float* __restrict__ w_att,  // [HID]
    float* __restrict__ attn_out,     // [B, SEQ] (zeroed here)
    float* __restrict__ ws_exp,
    float* __restrict__ ws_sum,
    int2*  __restrict__ ws_win,
    float* __restrict__ ws_ctx)
{
    const int blk = blockIdx.x;
    const int b   = blk >> 3;
    const int s   = blk & 7;
    const int tid = threadIdx.x;

    __shared__ float  hs[HID];
    __shared__ float  wa[HID];
    __shared__ double wred[4];
    __shared__ float  partial[256];
    __shared__ float  es[SLROWS];
    __shared__ int    win_s[2];

    hs[tid] = h_t[b * HID + tid];
    wa[tid] = w_att[tid];

    // ---- zero this block's 1024-float segment of the attn row
    {
        float4* az = (float4*)(attn_out + (size_t)b * SEQ + (size_t)s * 1024);
        az[tid] = make_float4(0.f, 0.f, 0.f, 0.f);
    }
    __syncthreads();

    // ---- p_t (redundant per block): thread = output dim j, f64 accum
    {
        const float4* wrow = (const float4*)(W_p + (size_t)tid * HID);
        double a0 = 0.0, a1 = 0.0, a2 = 0.0, a3 = 0.0;
#pragma unroll 4
        for (int k = 0; k < 64; k += 4) {
            float4 w0 = wrow[k], w1 = wrow[k+1], w2 = wrow[k+2], w3 = wrow[k+3];
            const float* h4 = &hs[4 * k];
            a0 += (double)w0.x*h4[0]  + (double)w0.y*h4[1]  + (double)w0.z*h4[2]  + (double)w0.w*h4[3];
            a1 += (double)w1.x*h4[4]  + (double)w1.y*h4[5]  + (double)w1.z*h4[6]  + (double)w1.w*h4[7];
            a2 += (double)w2.x*h4[8]  + (double)w2.y*h4[9]  + (double)w2.z*h4[10] + (double)w2.w*h4[11];
            a3 += (double)w3.x*h4[12] + (double)w3.y*h4[13] + (double)w3.z*h4[14] + (double)w3.w*h4[15];
        }
        float  t   = tanhf((float)(a0 + a1 + a2 + a3));
        double val = (double)t * (double)v_p[tid];
        for (int off = 32; off > 0; off >>= 1) val += __shfl_down(val, off, 64);
        if ((tid & 63) == 0) wred[tid >> 6] = val;
    }
    __syncthreads();
    if (tid == 0) {
        double x  = wred[0] + wred[1] + wred[2] + wred[3];
        float  xf = (float)x;
        float  sg = 1.0f / (1.0f + expf(-xf));     // sigmoid
        float  p  = (float)SEQ * sg;
        int pr = (int)rintf(p);                    // round-half-even == jnp.round
        pr = min(max(pr, 0), SEQ - 1);
        win_s[0] = max(pr - WIN, 0);
        win_s[1] = min(pr + WIN, SEQ);
        if (s == 0) ws_win[b] = make_int2(win_s[0], win_s[1]);
    }
    __syncthreads();

    const int start = win_s[0];
    const int end   = win_s[1];
    const int g0    = start + s * SLROWS;          // first global row of this slice

    // ---- scores: 8 threads per row, 32-float segments
    {
        const int r   = tid >> 3;                  // 0..31
        const int seg = tid & 7;
        const int g   = g0 + r;
        const int gc  = (g < end) ? g : start;     // clamp to valid row
        const float4* rowp = (const float4*)(enc + ((size_t)b * SEQ + gc) * HID + seg * 32);
        const float*  w4   = &wa[seg * 32];
        float sc = 0.f;
#pragma unroll
        for (int k = 0; k < 8; ++k) {
            float4 e = rowp[k];
            sc += e.x * w4[k*4+0] + e.y * w4[k*4+1] + e.z * w4[k*4+2] + e.w * w4[k*4+3];
        }
        partial[tid] = sc;
    }
    __syncthreads();

    if (tid < SLROWS) {
        const int base = tid * 8;
        float scr = 0.f;
#pragma unroll
        for (int k = 0; k < 8; ++k) scr += partial[base + k];
        const int g = g0 + tid;
        float ev = (g < end) ? expf(scr) : 0.f;    // no max-sub: scores ~N(0,1)
        es[tid] = ev;
        ws_exp[b * 256 + s * SLROWS + tid] = ev;
    }
    __syncthreads();

    if (tid == 0) {                                // fixed-order slice sum
        float sm = 0.f;
#pragma unroll
        for (int k = 0; k < SLROWS; ++k) sm += es[k];
        ws_sum[b * NSL + s] = sm;
    }

    // ---- partial context: thread = h dim, 32 rows, coalesced
    {
        float acc = 0.f;
        if (g0 + SLROWS - 1 < end) {               // all rows valid
            const float* basep = enc + ((size_t)b * SEQ + g0) * HID + tid;
#pragma unroll
            for (int i = 0; i < SLROWS; ++i)
                acc += es[i] * basep[(size_t)i * HID];
        } else {                                   // tail: clamp (es[i]==0 there)
#pragma unroll
            for (int i = 0; i < SLROWS; ++i) {
                int g  = g0 + i;
                int gc = (g < end) ? g : start;
                acc += es[i] * enc[((size_t)b * SEQ + gc) * HID + tid];
            }
        }
        ws_ctx[((size_t)b * NSL + s) * HID + tid] = acc;
    }
}

// ---------------------------------------------------------------------------
// K_final: 32 blocks x 256 threads. Combine partials, normalize, write out.
// ---------------------------------------------------------------------------
__global__ __launch_bounds__(256) void k_final(
    const float* __restrict__ ws_exp,
    const float* __restrict__ ws_sum,
    const int2*  __restrict__ ws_win,
    const float* __restrict__ ws_ctx,
    float* __restrict__ ctx_out,      // [B, HID]
    float* __restrict__ attn_out)     // [B, SEQ]
{
    const int b   = blockIdx.x;
    const int tid = threadIdx.x;

    __shared__ float inv_s;
    __shared__ int   win_s[2];

    if (tid == 0) {
        int2 w = ws_win[b];
        win_s[0] = w.x; win_s[1] = w.y;
        float dsum = 0.f;
#pragma unroll
        for (int k = 0; k < NSL; ++k) dsum += ws_sum[b * NSL + k];
        inv_s = 1.0f / dsum;
    }
    __syncthreads();

    const float inv = inv_s;
    float acc = 0.f;
#pragma unroll
    for (int k = 0; k < NSL; ++k)
        acc += ws_ctx[((size_t)b * NSL + k) * HID + tid];
    ctx_out[b * HID + tid] = acc * inv;

    const int start = win_s[0];
    const int L     = win_s[1] - win_s[0];
    if (tid < L)
        attn_out[(size_t)b * SEQ + start + tid] = ws_exp[b * 256 + tid] * inv;
}

extern "C" void kernel_launch(void* const* d_in, const int* in_sizes, int n_in,
                              void* d_out, int out_size, void* d_ws, size_t ws_size,
                              hipStream_t stream) {
    const float* h_t   = (const float*)d_in[0];   // [B, HID]
    const float* enc   = (const float*)d_in[1];   // [B, SEQ, HID]
    const float* W_p   = (const float*)d_in[2];   // [HID, HID]
    const float* v_p   = (const float*)d_in[3];   // [HID]
    const float* w_att = (const float*)d_in[4];   // [HID]

    float* ctx_out  = (float*)d_out;                  // [B, HID]
    float* attn_out = (float*)d_out + BATCH * HID;    // [B, SEQ]

    char*  ws     = (char*)d_ws;
    float* ws_exp = (float*)(ws + WS_EXP_OFF);
    float* ws_sum = (float*)(ws + WS_SUM_OFF);
    int2*  ws_win = (int2*) (ws + WS_WIN_OFF);
    float* ws_ctx = (float*)(ws + WS_CTX_OFF);

    k_slice<<<BATCH * NSL, 256, 0, stream>>>(
        h_t, enc, W_p, v_p, w_att, attn_out, ws_exp, ws_sum, ws_win, ws_ctx);
    k_final<<<BATCH, 256, 0, stream>>>(
        ws_exp, ws_sum, ws_win, ws_ctx, ctx_out, attn_out);
}

// Round 6
// 16.112 us; speedup vs baseline: 3.0443x; 1.1892x over previous
//
#include <hip/hip_runtime.h>
#include <math.h>

#define BATCH   32
#define SEQ     8192
#define HID     256
#define WIN     128
#define NSL     8            // window slices (blocks) per batch in K2
#define SLROWS  32           // window rows per slice
#define NQ      8            // j-slices per batch in K1
#define TPAD    260          // padded LDS tile row (floats) -> bank-floor stores

// ws layout (bytes):
//   ws_pt  : double[BATCH*NQ]       @ 0       (2 KB)  j-slice partials of tanh@v_p
//   ws_exp : float[BATCH*256]       @ 2048    (32 KB) unnormalized exp(score)
//   ws_sum : float[BATCH*NSL]       @ 34816   (1 KB)  per-slice exp sums
//   ws_ctx : float[BATCH*NSL*HID]   @ 35840   (256 KB) per-slice context partials
#define WS_PT_OFF   0
#define WS_EXP_OFF  2048
#define WS_SUM_OFF  34816
#define WS_CTX_OFF  35840

// ---------------------------------------------------------------------------
// K1: 256 blocks = 32 batches x 8 j-slices, 256 threads.
// Each block: zero 1/256 of attn_out (1 float4/thread), f64 partial of
// tanh(W_p h).v_p over 32 output dims (32 KB of W_p per block).
// ---------------------------------------------------------------------------
__global__ __launch_bounds__(256) void k1_pt(
    const float* __restrict__ h_t,    // [B, HID]
    const float* __restrict__ W_p,    // [HID, HID]
    const float* __restrict__ v_p,    // [HID]
    float* __restrict__ attn_out,     // [B, SEQ] (zeroed here)
    double* __restrict__ ws_pt)       // [B*NQ]
{
    const int blk = blockIdx.x;
    const int b   = blk >> 3;
    const int q   = blk & 7;          // j-slice: dims q*32 .. q*32+31
    const int tid = threadIdx.x;

    __shared__ float  hs[HID];
    __shared__ double red[256];

    hs[tid] = h_t[b * HID + tid];

    // zero attn: 65536 float4 total over 65536 threads -> exactly one each
    ((float4*)attn_out)[(size_t)blk * 256 + tid] = make_float4(0.f, 0.f, 0.f, 0.f);
    __syncthreads();

    // thread: jl = tid>>3 (0..31), ks = tid&7 (k-segment of 32 floats)
    const int jl = tid >> 3;
    const int j  = q * 32 + jl;
    const int ks = tid & 7;
    const float4* wrow = (const float4*)(W_p + (size_t)j * HID + ks * 32);
    const float*  h4   = &hs[ks * 32];
    double acc = 0.0;
#pragma unroll
    for (int k = 0; k < 8; ++k) {
        float4 w = wrow[k];
        acc += (double)w.x * h4[k*4+0] + (double)w.y * h4[k*4+1]
             + (double)w.z * h4[k*4+2] + (double)w.w * h4[k*4+3];
    }
    red[tid] = acc;
    __syncthreads();

    if (tid < 32) {
        double s = 0.0;
#pragma unroll
        for (int k = 0; k < 8; ++k) s += red[tid * 8 + k];
        float  t   = tanhf((float)s);
        double val = (double)t * (double)v_p[q * 32 + tid];
        // reduce 32 lanes (all within wave 0)
        for (int off = 16; off > 0; off >>= 1)
            val += __shfl_down(val, off, 32);
        if (tid == 0) ws_pt[b * NQ + q] = val;
    }
}

// window bounds from the NQ f64 partials
__device__ __forceinline__ void window_from_partials(const double* ws_pt, int b,
                                                     int* start, int* end) {
    double x = 0.0;
#pragma unroll
    for (int k = 0; k < NQ; ++k) x += ws_pt[b * NQ + k];
    float xf = (float)x;
    float sg = 1.0f / (1.0f + expf(-xf));          // sigmoid
    float p  = (float)SEQ * sg;
    int pr = (int)rintf(p);                        // round-half-even == jnp.round
    pr = min(max(pr, 0), SEQ - 1);
    *start = max(pr - WIN, 0);
    *end   = min(pr + WIN, SEQ);
}

// ---------------------------------------------------------------------------
// K2: 256 blocks = 32 batches x 8 window-slices, 256 threads.
// Stages its 32 enc rows into LDS during the score pass (enc read ONCE),
// then scores -> exp -> fixed-order slice sum -> ctx partial from LDS.
// ---------------------------------------------------------------------------
__global__ __launch_bounds__(256) void k2_scores_ctx(
    const float* __restrict__ enc,    // [B, SEQ, HID]
    const float* __restrict__ w_att,  // [HID]
    const double* __restrict__ ws_pt, // [B*NQ]
    float* __restrict__ ws_exp,       // [B*256]
    float* __restrict__ ws_sum,       // [B*NSL]
    float* __restrict__ ws_ctx)       // [B*NSL*HID]
{
    const int blk = blockIdx.x;
    const int b   = blk >> 3;
    const int s   = blk & 7;
    const int tid = threadIdx.x;

    __shared__ float  wa[HID];
    __shared__ float  tile[SLROWS][TPAD];   // padded: b128 stores hit bank floor
    __shared__ float  partial[256];
    __shared__ float  es[SLROWS];
    __shared__ double redd[NQ];
    __shared__ int    win_s[2];

    wa[tid] = w_att[tid];
    if (tid < NQ) redd[tid] = ws_pt[b * NQ + tid];   // parallel dependency head
    __syncthreads();
    if (tid == 0) {
        double x = 0.0;
#pragma unroll
        for (int k = 0; k < NQ; ++k) x += redd[k];
        float xf = (float)x;
        float sg = 1.0f / (1.0f + expf(-xf));
        float p  = (float)SEQ * sg;
        int pr = (int)rintf(p);
        pr = min(max(pr, 0), SEQ - 1);
        win_s[0] = max(pr - WIN, 0);
        win_s[1] = min(pr + WIN, SEQ);
    }
    __syncthreads();

    const int start = win_s[0];
    const int end   = win_s[1];
    const int g0    = start + s * SLROWS;

    // ---- score pass + LDS staging: 8 threads/row, 32-float segments
    {
        const int r  = tid >> 3;                   // 0..31
        const int ks = tid & 7;
        const int g  = g0 + r;
        const int gc = (g < end) ? g : start;      // clamp (es=0 kills it later)
        const float4* rowp = (const float4*)(enc + ((size_t)b * SEQ + gc) * HID + ks * 32);
        const float*  w4   = &wa[ks * 32];
        float4* trow = (float4*)&tile[r][ks * 32];
        float sc = 0.f;
#pragma unroll
        for (int k = 0; k < 8; ++k) {
            float4 e = rowp[k];
            trow[k] = e;
            sc += e.x * w4[k*4+0] + e.y * w4[k*4+1] + e.z * w4[k*4+2] + e.w * w4[k*4+3];
        }
        partial[tid] = sc;
    }
    __syncthreads();

    if (tid < SLROWS) {
        float scr = 0.f;
#pragma unroll
        for (int k = 0; k < 8; ++k) scr += partial[tid * 8 + k];
        const int g = g0 + tid;
        float ev = (g < end) ? expf(scr) : 0.f;    // no max-sub: scores ~N(0,1)
        es[tid] = ev;
        ws_exp[b * 256 + s * SLROWS + tid] = ev;
    }
    __syncthreads();

    if (tid == 0) {                                // fixed-order slice sum
        float sm = 0.f;
#pragma unroll
        for (int k = 0; k < SLROWS; ++k) sm += es[k];
        ws_sum[b * NSL + s] = sm;
    }

    // ---- ctx partial from LDS: thread = h dim, 32 rows
    {
        float acc = 0.f;
#pragma unroll
        for (int i = 0; i < SLROWS; ++i)
            acc += es[i] * tile[i][tid];
        ws_ctx[((size_t)b * NSL + s) * HID + tid] = acc;
    }
}

// ---------------------------------------------------------------------------
// K3: 32 blocks x 256 threads. Combine partials, normalize, write outputs.
// ---------------------------------------------------------------------------
__global__ __launch_bounds__(256) void k3_finalize(
    const double* __restrict__ ws_pt,
    const float* __restrict__ ws_exp,
    const float* __restrict__ ws_sum,
    const float* __restrict__ ws_ctx,
    float* __restrict__ ctx_out,      // [B, HID]
    float* __restrict__ attn_out)     // [B, SEQ]
{
    const int b   = blockIdx.x;
    const int tid = threadIdx.x;

    __shared__ int   win_s[2];
    __shared__ float inv_s;

    if (tid == 0) {
        int st, en;
        window_from_partials(ws_pt, b, &st, &en);
        win_s[0] = st; win_s[1] = en;
        float dsum = 0.f;
#pragma unroll
        for (int k = 0; k < NSL; ++k) dsum += ws_sum[b * NSL + k];
        inv_s = 1.0f / dsum;
    }
    __syncthreads();

    const float inv = inv_s;
    float acc = 0.f;
#pragma unroll
    for (int k = 0; k < NSL; ++k)
        acc += ws_ctx[((size_t)b * NSL + k) * HID + tid];
    ctx_out[b * HID + tid] = acc * inv;

    const int start = win_s[0];
    const int L     = win_s[1] - win_s[0];
    if (tid < L)
        attn_out[(size_t)b * SEQ + start + tid] = ws_exp[b * 256 + tid] * inv;
}

extern "C" void kernel_launch(void* const* d_in, const int* in_sizes, int n_in,
                              void* d_out, int out_size, void* d_ws, size_t ws_size,
                              hipStream_t stream) {
    const float* h_t   = (const float*)d_in[0];   // [B, HID]
    const float* enc   = (const float*)d_in[1];   // [B, SEQ, HID]
    const float* W_p   = (const float*)d_in[2];   // [HID, HID]
    const float* v_p   = (const float*)d_in[3];   // [HID]
    const float* w_att = (const float*)d_in[4];   // [HID]

    float* ctx_out  = (float*)d_out;                  // [B, HID]
    float* attn_out = (float*)d_out + BATCH * HID;    // [B, SEQ]

    char*   ws     = (char*)d_ws;
    double* ws_pt  = (double*)(ws + WS_PT_OFF);
    float*  ws_exp = (float*) (ws + WS_EXP_OFF);
    float*  ws_sum = (float*) (ws + WS_SUM_OFF);
    float*  ws_ctx = (float*) (ws + WS_CTX_OFF);

    k1_pt<<<BATCH * NQ, 256, 0, stream>>>(h_t, W_p, v_p, attn_out, ws_pt);
    k2_scores_ctx<<<BATCH * NSL, 256, 0, stream>>>(enc, w_att, ws_pt, ws_exp, ws_sum, ws_ctx);
    k3_finalize<<<BATCH, 256, 0, stream>>>(ws_pt, ws_exp, ws_sum, ws_ctx, ctx_out, attn_out);
}